// Round 28
// baseline (87.743 us; speedup 1.0000x reference)
//
#include <hip/hip_runtime.h>

// DialogueGCN on MI355X — round 27 = R26/R24 (85.3us, confirmed best) + float2
// score-dot loads in gather1 (xm global 8B/lane + ys LDS float2; halves the
// score-phase load issue count). All else byte-identical to R26.

#define NN 4096

typedef __bf16 bf16x8 __attribute__((ext_vector_type(8)));
typedef float f32x4 __attribute__((ext_vector_type(4)));
typedef unsigned short u16;
typedef unsigned int u32;

__device__ __forceinline__ u16 f2bf(float f) {
  unsigned u = __float_as_uint(f);
  unsigned r = u + 0x7FFFu + ((u >> 16) & 1u);
  return (u16)(r >> 16);
}
__device__ __forceinline__ float bf2f(u16 h) {
  return __uint_as_float(((unsigned)h) << 16);
}
__device__ __forceinline__ float blo(u32 v) { return __uint_as_float(v << 16); }
__device__ __forceinline__ float bhi(u32 v) { return __uint_as_float(v & 0xffff0000u); }
__device__ __forceinline__ u32 packbf(float a, float b) {
  return (u32)f2bf(a) | ((u32)f2bf(b) << 16);
}

__device__ __forceinline__ void gload_lds16(const u16* g, u16* l) {
  __builtin_amdgcn_global_load_lds(
      (const __attribute__((address_space(1))) void*)g,
      (__attribute__((address_space(3))) void*)l, 16, 0, 0);
}

// ---------------- fused prep (grid 2624): transposes + grid-stride main ----------------
__global__ __launch_bounds__(256) void prep_fused(
    const float* __restrict__ x, const float* __restrict__ w_att,
    const float* __restrict__ w_gc1, const float* __restrict__ w_aggr1,
    const float* __restrict__ w_gc2, const float* __restrict__ w_aggr2,
    const int* __restrict__ spk, u16* __restrict__ Aatt, u16* __restrict__ Batt,
    u16* __restrict__ Wt1, u16* __restrict__ Wt2, float* __restrict__ xp,
    u32* __restrict__ xWg, u32* __restrict__ h1Wg, int* __restrict__ spkp) {
  __shared__ float t[64][65];
  const int b = blockIdx.x, tid = threadIdx.x;
  if (b < 576) {
    const int r = tid >> 6, c = tid & 63;
    if (b < 512) {
      const int lay = b >> 8, tb = b & 255;
      const int jt = tb >> 3, kt = tb & 7;
      const float* g = lay ? w_gc2 : w_gc1;
      const float* wa = lay ? w_aggr2 : w_aggr1;
      u16* Wt = lay ? Wt2 : Wt1;
      const int p = (jt * 64) >> 9;
      const int jj0 = (jt * 64) & 511;
      const int k0 = kt * 64;
#pragma unroll
      for (int i = 0; i < 16; ++i) {
        int rr = r + i * 4;
        size_t o = (size_t)(k0 + rr) * 512 + jj0 + c;
        float v;
        if (p == 0)      v = g[o] - g[262144 + o];
        else if (p == 1) v = g[524288 + o] - g[786432 + o];
        else if (p == 2) v = g[262144 + o] + g[786432 + o];
        else             v = wa[o];
        t[c][rr] = v;
      }
      __syncthreads();
#pragma unroll
      for (int i = 0; i < 16; ++i) {
        int jl = r + i * 4;
        Wt[(size_t)(jt * 64 + jl) * 512 + k0 + c] = f2bf(t[jl][c]);
      }
    } else {
      const int tb = b - 512;
      const int et = tb >> 3, jt2 = tb & 7;
      const int e0 = et * 64, j0 = jt2 * 64;
#pragma unroll
      for (int i = 0; i < 16; ++i) {
        int rr = r + i * 4;
        t[c][rr] = w_att[(size_t)(e0 + rr) * 512 + j0 + c];
      }
      __syncthreads();
#pragma unroll
      for (int i = 0; i < 16; ++i) {
        int jl = r + i * 4;
        float v = t[jl][c];
        u16 hi = f2bf(v), lo = f2bf(v - bf2f(hi));
        u16* row = Batt + (size_t)(j0 + jl) * 1024;  // [Whi | Wlo]
        row[e0 + c] = hi;
        row[512 + e0 + c] = lo;
      }
    }
    return;
  }
  for (int vb = b - 576; vb < 8529; vb += 2048) {
    if (vb < 8192) {
      int s = vb >> 3;
      int r = 512 * (vb & 7) + (s >> 1);  // writer XCD == r>>9
      int c = ((s & 1) << 8) + tid;
      float v = x[(size_t)r * 512 + c];
      u16 hi = f2bf(v), lo = f2bf(v - bf2f(hi));
      u16* row = Aatt + (size_t)r * 1024;  // [hi | lo]
      row[c] = hi;
      row[512 + c] = lo;
      xp[(size_t)(r + 16) * 512 + c] = v;
    } else if (vb < 8256) {
      int idx = (vb - 8192) * 256 + tid;
      int g = idx >> 9, c = idx & 511;
      int row = (g < 16) ? g : 4112 + (g - 16);
      xp[(size_t)row * 512 + c] = 0.f;
    } else if (vb < 8384) {
      int idx = (vb - 8256) * 256 + tid;
      int g = idx >> 10, c = idx & 1023;
      int row = (g < 16) ? g : 4112 + (g - 16);
      xWg[(size_t)row * 1024 + c] = 0;
    } else if (vb < 8512) {
      int idx = (vb - 8384) * 256 + tid;
      int g = idx >> 10, c = idx & 1023;
      int row = (g < 16) ? g : 4112 + (g - 16);
      h1Wg[(size_t)row * 1024 + c] = 0;
    } else {
      int idx = (vb - 8512) * 256 + tid;
      if (idx < 4128)
        spkp[idx] = (idx >= 16 && idx < 4112) ? spk[idx - 16] : -9;
    }
  }
}

// Row-aligned XCD swizzle (R17)
__device__ __forceinline__ void xcd_align(int gx, int& bx, int& by) {
  int lid = by * gx + bx;
  int xcd = lid & 7;
  int s = lid >> 3;
  int q = s / gx;
  bx = s - q * gx;
  by = xcd * 4 + q;
}

// ---------------- 128x128 GEMM core — BK=64, swizzled, dbuf, counted vmcnt ----------------
__device__ __forceinline__ void gemm_core(const u16* __restrict__ A, const u16* __restrict__ Bt,
                                          int K, int lda, int ldb, size_t bm, size_t bn,
                                          u16 (&As)[2][8192], u16 (&Bs)[2][8192],
                                          f32x4 (&acc)[4][4]) {
  const int tid = threadIdx.x;
  const int lane = tid & 63;
  const int wave = tid >> 6;
  const int wr = wave >> 1, wc = wave & 1;
  const int arow = wr * 64 + (lane & 15);
  const int bcol = wc * 64 + (lane & 15);
  const int nt = K >> 6;

  auto STAGE = [&](int t, int bi) {
    const int k0 = t << 6;
#pragma unroll
    for (int c4 = 0; c4 < 4; ++c4) {
      const int o = (c4 * 256 + tid) * 16;
      const int r = o >> 7;
      const int sc = (((o >> 4) & 7) ^ (r & 7)) << 3;
      gload_lds16(A + (bm + r) * lda + k0 + sc, &As[bi][o >> 1]);
      gload_lds16(Bt + (bn + r) * ldb + k0 + sc, &Bs[bi][o >> 1]);
    }
  };

  STAGE(0, 0);
  for (int t = 0; t < nt; ++t) {
    const int cur = t & 1;
    if (t + 1 < nt) {
      STAGE(t + 1, cur ^ 1);
      asm volatile("s_waitcnt vmcnt(8)" ::: "memory");
    } else {
      asm volatile("s_waitcnt vmcnt(0)" ::: "memory");
    }
    __builtin_amdgcn_s_barrier();
    asm volatile("" ::: "memory");
    bf16x8 af[4][2], bfr[4][2];
#pragma unroll
    for (int i = 0; i < 4; ++i)
#pragma unroll
      for (int ks = 0; ks < 2; ++ks) {
        const int ar = arow + i * 16;
        const int ac = ((ks * 4 + (lane >> 4)) ^ (ar & 7)) << 4;
        af[i][ks] = *(const bf16x8*)((const char*)&As[cur][0] + ar * 128 + ac);
        const int br = bcol + i * 16;
        const int bc = ((ks * 4 + (lane >> 4)) ^ (br & 7)) << 4;
        bfr[i][ks] = *(const bf16x8*)((const char*)&Bs[cur][0] + br * 128 + bc);
      }
#pragma unroll
    for (int ks = 0; ks < 2; ++ks)
#pragma unroll
      for (int i = 0; i < 4; ++i)
#pragma unroll
        for (int j = 0; j < 4; ++j)
          acc[i][j] = __builtin_amdgcn_mfma_f32_16x16x32_bf16(af[i][ks], bfr[j][ks],
                                                              acc[i][j], 0, 0, 0);
    asm volatile("s_waitcnt lgkmcnt(0)" ::: "memory");
    __builtin_amdgcn_sched_barrier(0);
    __builtin_amdgcn_s_barrier();
  }
}

// fat GEMM: bx<12 -> y partial kp=bx>>2 (K=512 slice of split-bf16); else xW panel.
__global__ __launch_bounds__(256, 2) void fat_gemm(const u16* __restrict__ Aatt,
                                                   const u16* __restrict__ Wt1,
                                                   const u16* __restrict__ Batt,
                                                   u16* __restrict__ xW, float* __restrict__ y) {
  __shared__ u16 As[2][8192];
  __shared__ u16 Bs[2][8192];
  f32x4 acc[4][4] = {};
  const int tid = threadIdx.x;
  const int lane = tid & 63;
  const int wave = tid >> 6;
  const int wr = wave >> 1, wc = wave & 1;
  int bx = blockIdx.x, by = blockIdx.y;
  xcd_align(28, bx, by);
  const size_t bm = (size_t)by * 128;
  const bool yp = bx < 12;
  const int kp = yp ? (bx >> 2) : 0;
  const size_t bn = yp ? (size_t)(bx & 3) * 128 : (size_t)(bx - 12) * 128;

  if (yp) {
    const int aoff = (kp == 1) ? 512 : 0;
    const int boff = (kp == 2) ? 512 : 0;
    gemm_core(Aatt + aoff, Batt + boff, 512, 1024, 1024, bm, bn, As, Bs, acc);
  } else {
    gemm_core(Aatt, Wt1, 512, 1024, 512, bm, bn, As, Bs, acc);
  }

  const size_t crow = bm + wr * 64 + ((lane >> 4) * 4);
  const size_t ccol = bn + wc * 64 + (lane & 15);
  float* yk = y + (size_t)kp * NN * 512;
#pragma unroll
  for (int i = 0; i < 4; ++i)
#pragma unroll
    for (int j = 0; j < 4; ++j)
#pragma unroll
      for (int b = 0; b < 4; ++b) {
        size_t r = crow + i * 16 + b, c = ccol + j * 16;
        if (yp)
          yk[r * 512 + c] = acc[i][j][b];
        else
          xW[r * 2048 + c] = f2bf(acc[i][j][b]);
      }
}

// layer-2 GEMM: h1W = h1 @ Wt2^T, K=512, bf16 out, ldc=2048
__global__ __launch_bounds__(256, 2) void gemm_l2(const u16* __restrict__ h1,
                                                  const u16* __restrict__ Wt2,
                                                  u16* __restrict__ h1W) {
  __shared__ u16 As[2][8192];
  __shared__ u16 Bs[2][8192];
  f32x4 acc[4][4] = {};
  const int tid = threadIdx.x;
  const int lane = tid & 63;
  const int wave = tid >> 6;
  const int wr = wave >> 1, wc = wave & 1;
  int bx = blockIdx.x, by = blockIdx.y;
  xcd_align(16, bx, by);
  const size_t bm = (size_t)by * 128;
  const size_t bn = (size_t)bx * 128;
  gemm_core(h1, Wt2, 512, 512, 512, bm, bn, As, Bs, acc);
  const size_t crow = bm + wr * 64 + ((lane >> 4) * 4);
  const size_t ccol = bn + wc * 64 + (lane & 15);
#pragma unroll
  for (int i = 0; i < 4; ++i)
#pragma unroll
    for (int j = 0; j < 4; ++j)
#pragma unroll
      for (int b = 0; b < 4; ++b) {
        size_t r = crow + i * 16 + b, c = ccol + j * 16;
        h1W[r * 2048 + c] = f2bf(acc[i][j][b]);
      }
}

// XCD-contiguous row mapping (reader XCD = n>>9)
__device__ __forceinline__ int xcd_row(int b) { return (b & 7) * 512 + (b >> 3); }

// ---------------- gather1: scores + softmax + banded aggregate + relu ----------------
__global__ void gather1(const float* __restrict__ xp, const float* __restrict__ y,
                        const u16* __restrict__ xW, const int* __restrict__ spkp,
                        float* __restrict__ attn, u16* __restrict__ h1) {
  const int n = xcd_row(blockIdx.x);
  const int tid = threadIdx.x;
  __shared__ float ys[512];
  __shared__ float sc[21];
  __shared__ float av[21], apv[21], asv[21];
  __shared__ int sps[21];
  const int mysp = spkp[16 + n];
  {
    const float* y0 = y + (size_t)n * 512;
    const float* y1 = y0 + (size_t)NN * 512;
    const float* y2 = y1 + (size_t)NN * 512;
    ys[tid] = y0[tid] + y1[tid] + y2[tid];
    ys[tid + 256] = y0[tid + 256] + y1[tid + 256] + y2[tid + 256];
  }
  if (tid < 21) sps[tid] = spkp[16 + n - 10 + tid];
  __syncthreads();
  const int wave = tid >> 6, lane = tid & 63;
  for (int w = wave; w < 21; w += 4) {
    const float2* xm = (const float2*)(xp + (size_t)(n + 6 + w) * 512);
    const float2* ys2 = (const float2*)ys;
    float p = 0.f;
#pragma unroll
    for (int i = 0; i < 4; ++i) {
      float2 a = xm[lane + i * 64];
      float2 b = ys2[lane + i * 64];
      p += a.x * b.x + a.y * b.y;
    }
#pragma unroll
    for (int off = 32; off; off >>= 1) p += __shfl_xor(p, off, 64);
    if (lane == 0) sc[w] = p;
  }
  __syncthreads();
  if (tid < 64) {
    float v = (tid < 21) ? sc[tid] : -1e30f;
    float mx = v;
#pragma unroll
    for (int off = 32; off; off >>= 1) mx = fmaxf(mx, __shfl_xor(mx, off, 64));
    float e = (tid < 21) ? __expf(v - mx) : 0.f;
    float sum = e;
#pragma unroll
    for (int off = 32; off; off >>= 1) sum += __shfl_xor(sum, off, 64);
    if (tid < 21) {
      int m = n + tid - 10;
      float a = (0 <= m && m < NN) ? (e / sum) : 0.f;
      av[tid] = a;
      apv[tid] = (tid >= 10) ? a : 0.f;
      asv[tid] = (sps[tid] == mysp) ? a : 0.f;
      attn[(size_t)n * 24 + tid] = a;
    }
  }
  __syncthreads();
  const u32* xW32 = (const u32*)xW;
  u32 hv = xW32[(size_t)n * 1024 + 768 + tid];
  float a0 = blo(hv), a1 = bhi(hv);
#pragma unroll
  for (int w = 0; w < 10; ++w) {  // pred weight 0: 2 terms
    const u32* row = xW32 + (ptrdiff_t)(n - 10 + w) * 1024 + tid;
    u32 vs = row[256], va = row[512];
    float s2 = asv[w], a = av[w];
    a0 += s2 * blo(vs) + a * blo(va);
    a1 += s2 * bhi(vs) + a * bhi(va);
  }
#pragma unroll
  for (int w = 10; w < 21; ++w) {  // 3 terms
    const u32* row = xW32 + (ptrdiff_t)(n - 10 + w) * 1024 + tid;
    u32 vp = row[0], vs = row[256], va = row[512];
    float ap = apv[w], s2 = asv[w], a = av[w];
    a0 += ap * blo(vp) + s2 * blo(vs) + a * blo(va);
    a1 += ap * bhi(vp) + s2 * bhi(vs) + a * bhi(va);
  }
  ((u32*)(h1 + (size_t)n * 512))[tid] = packbf(fmaxf(a0, 0.f), fmaxf(a1, 0.f));
}

// ---------------- gather2: banded aggregate + relu -> fp32 out ----------------
__global__ void gather2(const u16* __restrict__ h1W, const float* __restrict__ attn,
                        const int* __restrict__ spkp, float* __restrict__ out) {
  const int n = xcd_row(blockIdx.x);
  const int tid = threadIdx.x;
  __shared__ float av[21], apv[21], asv[21];
  if (tid < 21) {
    float a = attn[(size_t)n * 24 + tid];
    int sp = spkp[16 + n - 10 + tid];
    av[tid] = a;
    apv[tid] = (tid >= 10) ? a : 0.f;
    asv[tid] = (sp == spkp[16 + n]) ? a : 0.f;
  }
  __syncthreads();
  const u32* hW32 = (const u32*)h1W;
  u32 hv = hW32[(size_t)n * 1024 + 768 + tid];
  float a0 = blo(hv), a1 = bhi(hv);
#pragma unroll
  for (int w = 0; w < 10; ++w) {
    const u32* row = hW32 + (ptrdiff_t)(n - 10 + w) * 1024 + tid;
    u32 vs = row[256], va = row[512];
    float s2 = asv[w], a = av[w];
    a0 += s2 * blo(vs) + a * blo(va);
    a1 += s2 * bhi(vs) + a * bhi(va);
  }
#pragma unroll
  for (int w = 10; w < 21; ++w) {
    const u32* row = hW32 + (ptrdiff_t)(n - 10 + w) * 1024 + tid;
    u32 vp = row[0], vs = row[256], va = row[512];
    float ap = apv[w], s2 = asv[w], a = av[w];
    a0 += ap * blo(vp) + s2 * blo(vs) + a * blo(va);
    a1 += ap * bhi(vp) + s2 * bhi(vs) + a * bhi(va);
  }
  float* o = out + (size_t)n * 512 + tid * 2;
  o[0] = fmaxf(a0, 0.f);
  o[1] = fmaxf(a1, 0.f);
}

// ---------------- launch ----------------
extern "C" void kernel_launch(void* const* d_in, const int* in_sizes, int n_in,
                              void* d_out, int out_size, void* d_ws, size_t ws_size,
                              hipStream_t stream) {
  const float* x = (const float*)d_in[0];
  const int* spk = (const int*)d_in[1];
  const float* w_gc1 = (const float*)d_in[2];
  const float* w_gc2 = (const float*)d_in[3];
  const float* w_att = (const float*)d_in[4];
  const float* w_aggr1 = (const float*)d_in[5];
  const float* w_aggr2 = (const float*)d_in[6];

  char* p = (char*)d_ws;
  u16* Aatt = (u16*)p;  p += (size_t)NN * 1024 * 2;     // 8.4 MB [hi|lo]
  u16* Batt = (u16*)p;  p += (size_t)512 * 1024 * 2;    // 1.0 MB [Whi|Wlo]
  u16* Wt1 = (u16*)p;   p += (size_t)2048 * 512 * 2;    // 2.1 MB
  u16* Wt2 = (u16*)p;   p += (size_t)2048 * 512 * 2;    // 2.1 MB
  float* xp = (float*)p; p += (size_t)4128 * 512 * 4;   // 8.5 MB
  float* y = (float*)p; p += (size_t)3 * NN * 512 * 4;  // 25.2 MB
  float* attn = (float*)p; p += (size_t)NN * 24 * 4;    // 0.4 MB
  u16* xWg = (u16*)p;   p += (size_t)4128 * 2048 * 2;   // 16.9 MB
  u16* h1 = (u16*)p;    p += (size_t)NN * 512 * 2;      // 4.2 MB
  u16* h1Wg = (u16*)p;  p += (size_t)4128 * 2048 * 2;   // 16.9 MB
  int* spkp = (int*)p;  p += (size_t)4128 * 4;

  u16* xW = xWg + (size_t)16 * 2048;
  u16* h1W = h1Wg + (size_t)16 * 2048;

  prep_fused<<<2624, 256, 0, stream>>>(x, w_att, w_gc1, w_aggr1, w_gc2, w_aggr2, spk,
                                       Aatt, Batt, Wt1, Wt2, xp, (u32*)xWg, (u32*)h1Wg,
                                       spkp);

  fat_gemm<<<dim3(28, 32), 256, 0, stream>>>(Aatt, Wt1, Batt, xW, y);

  gather1<<<NN, 256, 0, stream>>>(xp, y, xW, spkp, attn, h1);

  gemm_l2<<<dim3(16, 32), 256, 0, stream>>>(h1, Wt2, h1W);

  gather2<<<NN, 256, 0, stream>>>(h1W, attn, spkp, (float*)d_out);
}

// Round 29
// 85.235 us; speedup vs baseline: 1.0294x; 1.0294x over previous
//
#include <hip/hip_runtime.h>

// DialogueGCN on MI355X — round 28 = exact revert to R24/R26 (85.3-85.4us,
// twice-confirmed best). R27's float2 score loads were neutral-to-negative
// (4-way LDS conflict offset halved issue count; phase is sub-noise anyway).
// FINAL configuration:
//   prep_fused (transposes + grid-stride, XCD row-aligned writers)
//   fat_gemm   (uniform K=512: 3 split-bf16 y slices + 16 xW panels, 896 blocks)
//   gather1    (fused scores/softmax + banded 3-panel aggregate, 4096 blocks)
//   gemm_l2    (h1 @ Wmix2)
//   gather2    (banded aggregate -> fp32 out)
// GEMM core: 128x128, BK=64, XOR-swizzled LDS (T2, both-sides), double-buffered
// with counted vmcnt(8) (T4), lgkmcnt(0)+sched_barrier before closing barrier.

#define NN 4096

typedef __bf16 bf16x8 __attribute__((ext_vector_type(8)));
typedef float f32x4 __attribute__((ext_vector_type(4)));
typedef unsigned short u16;
typedef unsigned int u32;

__device__ __forceinline__ u16 f2bf(float f) {
  unsigned u = __float_as_uint(f);
  unsigned r = u + 0x7FFFu + ((u >> 16) & 1u);
  return (u16)(r >> 16);
}
__device__ __forceinline__ float bf2f(u16 h) {
  return __uint_as_float(((unsigned)h) << 16);
}
__device__ __forceinline__ float blo(u32 v) { return __uint_as_float(v << 16); }
__device__ __forceinline__ float bhi(u32 v) { return __uint_as_float(v & 0xffff0000u); }
__device__ __forceinline__ u32 packbf(float a, float b) {
  return (u32)f2bf(a) | ((u32)f2bf(b) << 16);
}

__device__ __forceinline__ void gload_lds16(const u16* g, u16* l) {
  __builtin_amdgcn_global_load_lds(
      (const __attribute__((address_space(1))) void*)g,
      (__attribute__((address_space(3))) void*)l, 16, 0, 0);
}

// ---------------- fused prep (grid 2624): transposes + grid-stride main ----------------
__global__ __launch_bounds__(256) void prep_fused(
    const float* __restrict__ x, const float* __restrict__ w_att,
    const float* __restrict__ w_gc1, const float* __restrict__ w_aggr1,
    const float* __restrict__ w_gc2, const float* __restrict__ w_aggr2,
    const int* __restrict__ spk, u16* __restrict__ Aatt, u16* __restrict__ Batt,
    u16* __restrict__ Wt1, u16* __restrict__ Wt2, float* __restrict__ xp,
    u32* __restrict__ xWg, u32* __restrict__ h1Wg, int* __restrict__ spkp) {
  __shared__ float t[64][65];
  const int b = blockIdx.x, tid = threadIdx.x;
  if (b < 576) {
    const int r = tid >> 6, c = tid & 63;
    if (b < 512) {
      const int lay = b >> 8, tb = b & 255;
      const int jt = tb >> 3, kt = tb & 7;
      const float* g = lay ? w_gc2 : w_gc1;
      const float* wa = lay ? w_aggr2 : w_aggr1;
      u16* Wt = lay ? Wt2 : Wt1;
      const int p = (jt * 64) >> 9;
      const int jj0 = (jt * 64) & 511;
      const int k0 = kt * 64;
#pragma unroll
      for (int i = 0; i < 16; ++i) {
        int rr = r + i * 4;
        size_t o = (size_t)(k0 + rr) * 512 + jj0 + c;
        float v;
        if (p == 0)      v = g[o] - g[262144 + o];
        else if (p == 1) v = g[524288 + o] - g[786432 + o];
        else if (p == 2) v = g[262144 + o] + g[786432 + o];
        else             v = wa[o];
        t[c][rr] = v;
      }
      __syncthreads();
#pragma unroll
      for (int i = 0; i < 16; ++i) {
        int jl = r + i * 4;
        Wt[(size_t)(jt * 64 + jl) * 512 + k0 + c] = f2bf(t[jl][c]);
      }
    } else {
      const int tb = b - 512;
      const int et = tb >> 3, jt2 = tb & 7;
      const int e0 = et * 64, j0 = jt2 * 64;
#pragma unroll
      for (int i = 0; i < 16; ++i) {
        int rr = r + i * 4;
        t[c][rr] = w_att[(size_t)(e0 + rr) * 512 + j0 + c];
      }
      __syncthreads();
#pragma unroll
      for (int i = 0; i < 16; ++i) {
        int jl = r + i * 4;
        float v = t[jl][c];
        u16 hi = f2bf(v), lo = f2bf(v - bf2f(hi));
        u16* row = Batt + (size_t)(j0 + jl) * 1024;  // [Whi | Wlo]
        row[e0 + c] = hi;
        row[512 + e0 + c] = lo;
      }
    }
    return;
  }
  for (int vb = b - 576; vb < 8529; vb += 2048) {
    if (vb < 8192) {
      int s = vb >> 3;
      int r = 512 * (vb & 7) + (s >> 1);  // writer XCD == r>>9
      int c = ((s & 1) << 8) + tid;
      float v = x[(size_t)r * 512 + c];
      u16 hi = f2bf(v), lo = f2bf(v - bf2f(hi));
      u16* row = Aatt + (size_t)r * 1024;  // [hi | lo]
      row[c] = hi;
      row[512 + c] = lo;
      xp[(size_t)(r + 16) * 512 + c] = v;
    } else if (vb < 8256) {
      int idx = (vb - 8192) * 256 + tid;
      int g = idx >> 9, c = idx & 511;
      int row = (g < 16) ? g : 4112 + (g - 16);
      xp[(size_t)row * 512 + c] = 0.f;
    } else if (vb < 8384) {
      int idx = (vb - 8256) * 256 + tid;
      int g = idx >> 10, c = idx & 1023;
      int row = (g < 16) ? g : 4112 + (g - 16);
      xWg[(size_t)row * 1024 + c] = 0;
    } else if (vb < 8512) {
      int idx = (vb - 8384) * 256 + tid;
      int g = idx >> 10, c = idx & 1023;
      int row = (g < 16) ? g : 4112 + (g - 16);
      h1Wg[(size_t)row * 1024 + c] = 0;
    } else {
      int idx = (vb - 8512) * 256 + tid;
      if (idx < 4128)
        spkp[idx] = (idx >= 16 && idx < 4112) ? spk[idx - 16] : -9;
    }
  }
}

// Row-aligned XCD swizzle (R17)
__device__ __forceinline__ void xcd_align(int gx, int& bx, int& by) {
  int lid = by * gx + bx;
  int xcd = lid & 7;
  int s = lid >> 3;
  int q = s / gx;
  bx = s - q * gx;
  by = xcd * 4 + q;
}

// ---------------- 128x128 GEMM core — BK=64, swizzled, dbuf, counted vmcnt ----------------
__device__ __forceinline__ void gemm_core(const u16* __restrict__ A, const u16* __restrict__ Bt,
                                          int K, int lda, int ldb, size_t bm, size_t bn,
                                          u16 (&As)[2][8192], u16 (&Bs)[2][8192],
                                          f32x4 (&acc)[4][4]) {
  const int tid = threadIdx.x;
  const int lane = tid & 63;
  const int wave = tid >> 6;
  const int wr = wave >> 1, wc = wave & 1;
  const int arow = wr * 64 + (lane & 15);
  const int bcol = wc * 64 + (lane & 15);
  const int nt = K >> 6;

  auto STAGE = [&](int t, int bi) {
    const int k0 = t << 6;
#pragma unroll
    for (int c4 = 0; c4 < 4; ++c4) {
      const int o = (c4 * 256 + tid) * 16;
      const int r = o >> 7;
      const int sc = (((o >> 4) & 7) ^ (r & 7)) << 3;
      gload_lds16(A + (bm + r) * lda + k0 + sc, &As[bi][o >> 1]);
      gload_lds16(Bt + (bn + r) * ldb + k0 + sc, &Bs[bi][o >> 1]);
    }
  };

  STAGE(0, 0);
  for (int t = 0; t < nt; ++t) {
    const int cur = t & 1;
    if (t + 1 < nt) {
      STAGE(t + 1, cur ^ 1);
      asm volatile("s_waitcnt vmcnt(8)" ::: "memory");
    } else {
      asm volatile("s_waitcnt vmcnt(0)" ::: "memory");
    }
    __builtin_amdgcn_s_barrier();
    asm volatile("" ::: "memory");
    bf16x8 af[4][2], bfr[4][2];
#pragma unroll
    for (int i = 0; i < 4; ++i)
#pragma unroll
      for (int ks = 0; ks < 2; ++ks) {
        const int ar = arow + i * 16;
        const int ac = ((ks * 4 + (lane >> 4)) ^ (ar & 7)) << 4;
        af[i][ks] = *(const bf16x8*)((const char*)&As[cur][0] + ar * 128 + ac);
        const int br = bcol + i * 16;
        const int bc = ((ks * 4 + (lane >> 4)) ^ (br & 7)) << 4;
        bfr[i][ks] = *(const bf16x8*)((const char*)&Bs[cur][0] + br * 128 + bc);
      }
#pragma unroll
    for (int ks = 0; ks < 2; ++ks)
#pragma unroll
      for (int i = 0; i < 4; ++i)
#pragma unroll
        for (int j = 0; j < 4; ++j)
          acc[i][j] = __builtin_amdgcn_mfma_f32_16x16x32_bf16(af[i][ks], bfr[j][ks],
                                                              acc[i][j], 0, 0, 0);
    asm volatile("s_waitcnt lgkmcnt(0)" ::: "memory");
    __builtin_amdgcn_sched_barrier(0);
    __builtin_amdgcn_s_barrier();
  }
}

// fat GEMM: bx<12 -> y partial kp=bx>>2 (K=512 slice of split-bf16); else xW panel.
// Slices: kp0=(A+0,B+0) hi@Whi; kp1=(A+512,B+0) lo@Whi; kp2=(A+0,B+512) hi@Wlo.
__global__ __launch_bounds__(256, 2) void fat_gemm(const u16* __restrict__ Aatt,
                                                   const u16* __restrict__ Wt1,
                                                   const u16* __restrict__ Batt,
                                                   u16* __restrict__ xW, float* __restrict__ y) {
  __shared__ u16 As[2][8192];
  __shared__ u16 Bs[2][8192];
  f32x4 acc[4][4] = {};
  const int tid = threadIdx.x;
  const int lane = tid & 63;
  const int wave = tid >> 6;
  const int wr = wave >> 1, wc = wave & 1;
  int bx = blockIdx.x, by = blockIdx.y;
  xcd_align(28, bx, by);
  const size_t bm = (size_t)by * 128;
  const bool yp = bx < 12;
  const int kp = yp ? (bx >> 2) : 0;
  const size_t bn = yp ? (size_t)(bx & 3) * 128 : (size_t)(bx - 12) * 128;

  if (yp) {
    const int aoff = (kp == 1) ? 512 : 0;
    const int boff = (kp == 2) ? 512 : 0;
    gemm_core(Aatt + aoff, Batt + boff, 512, 1024, 1024, bm, bn, As, Bs, acc);
  } else {
    gemm_core(Aatt, Wt1, 512, 1024, 512, bm, bn, As, Bs, acc);
  }

  const size_t crow = bm + wr * 64 + ((lane >> 4) * 4);
  const size_t ccol = bn + wc * 64 + (lane & 15);
  float* yk = y + (size_t)kp * NN * 512;
#pragma unroll
  for (int i = 0; i < 4; ++i)
#pragma unroll
    for (int j = 0; j < 4; ++j)
#pragma unroll
      for (int b = 0; b < 4; ++b) {
        size_t r = crow + i * 16 + b, c = ccol + j * 16;
        if (yp)
          yk[r * 512 + c] = acc[i][j][b];
        else
          xW[r * 2048 + c] = f2bf(acc[i][j][b]);
      }
}

// layer-2 GEMM: h1W = h1 @ Wt2^T, K=512, bf16 out, ldc=2048
__global__ __launch_bounds__(256, 2) void gemm_l2(const u16* __restrict__ h1,
                                                  const u16* __restrict__ Wt2,
                                                  u16* __restrict__ h1W) {
  __shared__ u16 As[2][8192];
  __shared__ u16 Bs[2][8192];
  f32x4 acc[4][4] = {};
  const int tid = threadIdx.x;
  const int lane = tid & 63;
  const int wave = tid >> 6;
  const int wr = wave >> 1, wc = wave & 1;
  int bx = blockIdx.x, by = blockIdx.y;
  xcd_align(16, bx, by);
  const size_t bm = (size_t)by * 128;
  const size_t bn = (size_t)bx * 128;
  gemm_core(h1, Wt2, 512, 512, 512, bm, bn, As, Bs, acc);
  const size_t crow = bm + wr * 64 + ((lane >> 4) * 4);
  const size_t ccol = bn + wc * 64 + (lane & 15);
#pragma unroll
  for (int i = 0; i < 4; ++i)
#pragma unroll
    for (int j = 0; j < 4; ++j)
#pragma unroll
      for (int b = 0; b < 4; ++b) {
        size_t r = crow + i * 16 + b, c = ccol + j * 16;
        h1W[r * 2048 + c] = f2bf(acc[i][j][b]);
      }
}

// XCD-contiguous row mapping (reader XCD = n>>9)
__device__ __forceinline__ int xcd_row(int b) { return (b & 7) * 512 + (b >> 3); }

// ---------------- gather1: scores + softmax + banded aggregate + relu ----------------
__global__ void gather1(const float* __restrict__ xp, const float* __restrict__ y,
                        const u16* __restrict__ xW, const int* __restrict__ spkp,
                        float* __restrict__ attn, u16* __restrict__ h1) {
  const int n = xcd_row(blockIdx.x);
  const int tid = threadIdx.x;
  __shared__ float ys[512];
  __shared__ float sc[21];
  __shared__ float av[21], apv[21], asv[21];
  __shared__ int sps[21];
  const int mysp = spkp[16 + n];
  {
    const float* y0 = y + (size_t)n * 512;
    const float* y1 = y0 + (size_t)NN * 512;
    const float* y2 = y1 + (size_t)NN * 512;
    ys[tid] = y0[tid] + y1[tid] + y2[tid];
    ys[tid + 256] = y0[tid + 256] + y1[tid + 256] + y2[tid + 256];
  }
  if (tid < 21) sps[tid] = spkp[16 + n - 10 + tid];
  __syncthreads();
  const int wave = tid >> 6, lane = tid & 63;
  for (int w = wave; w < 21; w += 4) {
    const float* xm = xp + (size_t)(n + 6 + w) * 512;
    float p = 0.f;
#pragma unroll
    for (int i = 0; i < 8; ++i) p += xm[lane + i * 64] * ys[lane + i * 64];
#pragma unroll
    for (int off = 32; off; off >>= 1) p += __shfl_xor(p, off, 64);
    if (lane == 0) sc[w] = p;
  }
  __syncthreads();
  if (tid < 64) {
    float v = (tid < 21) ? sc[tid] : -1e30f;
    float mx = v;
#pragma unroll
    for (int off = 32; off; off >>= 1) mx = fmaxf(mx, __shfl_xor(mx, off, 64));
    float e = (tid < 21) ? __expf(v - mx) : 0.f;
    float sum = e;
#pragma unroll
    for (int off = 32; off; off >>= 1) sum += __shfl_xor(sum, off, 64);
    if (tid < 21) {
      int m = n + tid - 10;
      float a = (0 <= m && m < NN) ? (e / sum) : 0.f;
      av[tid] = a;
      apv[tid] = (tid >= 10) ? a : 0.f;
      asv[tid] = (sps[tid] == mysp) ? a : 0.f;
      attn[(size_t)n * 24 + tid] = a;
    }
  }
  __syncthreads();
  const u32* xW32 = (const u32*)xW;
  u32 hv = xW32[(size_t)n * 1024 + 768 + tid];
  float a0 = blo(hv), a1 = bhi(hv);
#pragma unroll
  for (int w = 0; w < 10; ++w) {  // pred weight 0: 2 terms
    const u32* row = xW32 + (ptrdiff_t)(n - 10 + w) * 1024 + tid;
    u32 vs = row[256], va = row[512];
    float s2 = asv[w], a = av[w];
    a0 += s2 * blo(vs) + a * blo(va);
    a1 += s2 * bhi(vs) + a * bhi(va);
  }
#pragma unroll
  for (int w = 10; w < 21; ++w) {  // 3 terms
    const u32* row = xW32 + (ptrdiff_t)(n - 10 + w) * 1024 + tid;
    u32 vp = row[0], vs = row[256], va = row[512];
    float ap = apv[w], s2 = asv[w], a = av[w];
    a0 += ap * blo(vp) + s2 * blo(vs) + a * blo(va);
    a1 += ap * bhi(vp) + s2 * bhi(vs) + a * bhi(va);
  }
  ((u32*)(h1 + (size_t)n * 512))[tid] = packbf(fmaxf(a0, 0.f), fmaxf(a1, 0.f));
}

// ---------------- gather2: banded aggregate + relu -> fp32 out ----------------
__global__ void gather2(const u16* __restrict__ h1W, const float* __restrict__ attn,
                        const int* __restrict__ spkp, float* __restrict__ out) {
  const int n = xcd_row(blockIdx.x);
  const int tid = threadIdx.x;
  __shared__ float av[21], apv[21], asv[21];
  if (tid < 21) {
    float a = attn[(size_t)n * 24 + tid];
    int sp = spkp[16 + n - 10 + tid];
    av[tid] = a;
    apv[tid] = (tid >= 10) ? a : 0.f;
    asv[tid] = (sp == spkp[16 + n]) ? a : 0.f;
  }
  __syncthreads();
  const u32* hW32 = (const u32*)h1W;
  u32 hv = hW32[(size_t)n * 1024 + 768 + tid];
  float a0 = blo(hv), a1 = bhi(hv);
#pragma unroll
  for (int w = 0; w < 10; ++w) {
    const u32* row = hW32 + (ptrdiff_t)(n - 10 + w) * 1024 + tid;
    u32 vs = row[256], va = row[512];
    float s2 = asv[w], a = av[w];
    a0 += s2 * blo(vs) + a * blo(va);
    a1 += s2 * bhi(vs) + a * bhi(va);
  }
#pragma unroll
  for (int w = 10; w < 21; ++w) {
    const u32* row = hW32 + (ptrdiff_t)(n - 10 + w) * 1024 + tid;
    u32 vp = row[0], vs = row[256], va = row[512];
    float ap = apv[w], s2 = asv[w], a = av[w];
    a0 += ap * blo(vp) + s2 * blo(vs) + a * blo(va);
    a1 += ap * bhi(vp) + s2 * bhi(vs) + a * bhi(va);
  }
  float* o = out + (size_t)n * 512 + tid * 2;
  o[0] = fmaxf(a0, 0.f);
  o[1] = fmaxf(a1, 0.f);
}

// ---------------- launch ----------------
extern "C" void kernel_launch(void* const* d_in, const int* in_sizes, int n_in,
                              void* d_out, int out_size, void* d_ws, size_t ws_size,
                              hipStream_t stream) {
  const float* x = (const float*)d_in[0];
  const int* spk = (const int*)d_in[1];
  const float* w_gc1 = (const float*)d_in[2];
  const float* w_gc2 = (const float*)d_in[3];
  const float* w_att = (const float*)d_in[4];
  const float* w_aggr1 = (const float*)d_in[5];
  const float* w_aggr2 = (const float*)d_in[6];

  char* p = (char*)d_ws;
  u16* Aatt = (u16*)p;  p += (size_t)NN * 1024 * 2;     // 8.4 MB [hi|lo]
  u16* Batt = (u16*)p;  p += (size_t)512 * 1024 * 2;    // 1.0 MB [Whi|Wlo]
  u16* Wt1 = (u16*)p;   p += (size_t)2048 * 512 * 2;    // 2.1 MB
  u16* Wt2 = (u16*)p;   p += (size_t)2048 * 512 * 2;    // 2.1 MB
  float* xp = (float*)p; p += (size_t)4128 * 512 * 4;   // 8.5 MB
  float* y = (float*)p; p += (size_t)3 * NN * 512 * 4;  // 25.2 MB
  float* attn = (float*)p; p += (size_t)NN * 24 * 4;    // 0.4 MB
  u16* xWg = (u16*)p;   p += (size_t)4128 * 2048 * 2;   // 16.9 MB
  u16* h1 = (u16*)p;    p += (size_t)NN * 512 * 2;      // 4.2 MB
  u16* h1Wg = (u16*)p;  p += (size_t)4128 * 2048 * 2;   // 16.9 MB
  int* spkp = (int*)p;  p += (size_t)4128 * 4;

  u16* xW = xWg + (size_t)16 * 2048;
  u16* h1W = h1Wg + (size_t)16 * 2048;

  prep_fused<<<2624, 256, 0, stream>>>(x, w_att, w_gc1, w_aggr1, w_gc2, w_aggr2, spk,
                                       Aatt, Batt, Wt1, Wt2, xp, (u32*)xWg, (u32*)h1Wg,
                                       spkp);

  fat_gemm<<<dim3(28, 32), 256, 0, stream>>>(Aatt, Wt1, Batt, xW, y);

  gather1<<<NN, 256, 0, stream>>>(xp, y, xW, spkp, attn, h1);

  gemm_l2<<<dim3(16, 32), 256, 0, stream>>>(h1, Wt2, h1W);

  gather2<<<NN, 256, 0, stream>>>(h1W, attn, spkp, (float*)d_out);
}